// Round 6
// baseline (7208.815 us; speedup 1.0000x reference)
//
#include <hip/hip_runtime.h>

// GRU T=512 B=256 D=512 H=512 O=256
// R6: R3's proven AGENT-atomic scan + static XCD grouping (wgid&7) with a
// self-verifying volatile(sc0)/L2-local fast path. No inline asm, no s_getreg,
// all spins bounded. Calibration ping-pong decides fast/slow per group via
// consensus over the proven AGENT path; slow mode == R3 exactly.

#define T_ 512
#define B_ 256
#define D_ 512
#define H_ 512
#define O_ 256

#define NWG 128
#define ROWS 16   // batch rows per wg
#define GC 64     // cols per gate per wg
#define GRP 8     // wgs per exchange group (one batch-group)
#define FBASE 8   // main-loop fast-flag values start here (calibration uses 1..3)

typedef __attribute__((ext_vector_type(8))) short short8;
typedef __attribute__((ext_vector_type(4))) float f32x4;

__device__ __forceinline__ unsigned short f2bf(float f) {
  unsigned u = __float_as_uint(f);
  u = (u + 0x7FFFu + ((u >> 16) & 1u)) >> 16;   // RNE
  return (unsigned short)u;
}
__device__ __forceinline__ float bf2f(unsigned short h) {
  return __uint_as_float(((unsigned)h) << 16);
}

// ---- prep: transpose weights to N-major bf16, combine biases, zero h + flags
__global__ void prep_kernel(const float* wz, const float* uz,
                            const float* wr, const float* ur,
                            const float* wh, const float* uh,
                            const float* bz, const float* ubz,
                            const float* br, const float* ubr,
                            const float* bh, const float* ubh,
                            unsigned short* WT, unsigned short* UT,
                            float* cb, unsigned short* hbuf, int* bar)
{
  int idx = blockIdx.x * 256 + threadIdx.x;
  if (idx < 1536 * 512) {
    int n = idx >> 9;          // output col 0..1535 (z|r|h)
    int k = idx & 511;
    int g = n >> 9;            // gate
    int c = n & 511;
    const float* w = (g == 0) ? wz : (g == 1) ? wr : wh;
    const float* u = (g == 0) ? uz : (g == 1) ? ur : uh;
    WT[idx] = f2bf(w[k * H_ + c]);   // WT[n][k] = W[k][n]
    UT[idx] = f2bf(u[k * H_ + c]);
  }
  if (idx < 1536) {
    int g = idx >> 9, c = idx & 511;
    const float* b  = (g == 0) ? bz  : (g == 1) ? br  : bh;
    const float* ub = (g == 0) ? ubz : (g == 1) ? ubr : ubh;
    cb[idx] = b[c] + ub[c];
  }
  if (idx < B_ * H_) hbuf[idx] = 0;
  if (idx < 12288) bar[idx] = 0;   // [0:4096) slow flags, [4096:8192) fast, [8192:12288) obs
}

// ---- persistent scan kernel
__global__ __launch_bounds__(256, 1) void gru_scan(
    const float* __restrict__ x,            // [T][B][D] fp32
    const unsigned short* __restrict__ WT,  // [1536][512] bf16 N-major
    const unsigned short* __restrict__ UT,  // [1536][512] bf16 N-major
    const float* __restrict__ cb,           // [1536] combined bias
    unsigned short* hbuf,                   // [B][H] bf16
    unsigned short* rhbuf,                  // [B][H] bf16
    int* bar)
{
  __shared__ __align__(16) unsigned short x_lds[2][ROWS][520];
  __shared__ __align__(16) unsigned short h_lds[ROWS][520];
  __shared__ __align__(8)  unsigned short pub[ROWS][GC];
  __shared__ int s_ok, s_fast;

  const int tid = threadIdx.x;
  const int wid = tid >> 6;       // wave 0..3
  const int lane = tid & 63;
  const int l16 = lane & 15;
  const int lhi = lane >> 4;      // 0..3

  // ---- static XCD-based grouping (deterministic; verified below) ----
  const int wgid = blockIdx.x;
  const int xcd = wgid & 7;       // expected XCD under round-robin dispatch
  const int sub = wgid >> 3;      // 0..15 within XCD
  const int bg = xcd * 2 + (sub >> 3);   // batch-group 0..15
  const int cg = sub & 7;                // member 0..7
  const int r0 = bg * ROWS;
  const int c0 = cg * GC;

  int* slowf = bar + bg * 256;           // 8 members x 32-int stride
  int* fastf = bar + 4096 + bg * 256;
  int* obsf  = bar + 8192 + bg * 256;

  // ---- calibration: does the volatile(sc0)/L2 path propagate within group? ----
  if (tid == 0) s_ok = 1;
  __syncthreads();
  for (int r = 1; r <= 3; ++r) {
    if (wid == 0) {
      if (lane == 0) *(volatile int*)(fastf + cg * 32) = r;
      int vote = 1;
      if (lane < GRP) {
        volatile int* p = (volatile int*)(fastf + lane * 32);
        int lim = 0;
        const int bound = (r == 1) ? (1 << 16) : 8192;  // round 1 absorbs launch skew
        while (*p < r) { if (++lim > bound) { vote = 0; break; } }
      }
      unsigned long long b = __ballot(vote);
      if (lane == 0) { if ((b & 0xFFull) != 0xFFull) s_ok = 0; }
    }
    __syncthreads();
  }
  if (tid == 0)
    __hip_atomic_store(obsf + cg * 32, s_ok ? 2 : 1,
                       __ATOMIC_RELAXED, __HIP_MEMORY_SCOPE_AGENT);
  if (wid == 0) {
    int vote = 1;
    if (lane < GRP) {
      int lim = 0, v = 0;
      while ((v = __hip_atomic_load(obsf + lane * 32,
                                    __ATOMIC_RELAXED, __HIP_MEMORY_SCOPE_AGENT)) == 0) {
        if (++lim > (1 << 20)) { v = 1; break; }   // fail-safe -> slow
        __builtin_amdgcn_s_sleep(1);
      }
      vote = (v == 2);
    }
    unsigned long long b = __ballot(vote);
    if (lane == 0) s_fast = ((b & 0xFFull) == 0xFFull) ? 1 : 0;
  }
  __syncthreads();
  const int fast = s_fast;   // wg-uniform; consensus-consistent across the group

  int* myslow = slowf + cg * 32;
  volatile int* myfast = (volatile int*)(fastf + cg * 32);

  const int ct = c0 + wid * 16;   // this wave's 16-col tile base (per gate)
  const unsigned short* WTz = WT + (size_t)(ct)        * 512;
  const unsigned short* WTr = WT + (size_t)(512 + ct)  * 512;
  const unsigned short* WTh = WT + (size_t)(1024 + ct) * 512;
  const unsigned short* UTz = UT + (size_t)(ct)        * 512;
  const unsigned short* UTr = UT + (size_t)(512 + ct)  * 512;
  const unsigned short* UTh = UT + (size_t)(1024 + ct) * 512;

  const int gcz  = ct + l16;      // this lane's gate column (0..511)
  const int lcol = ct - c0 + l16; // 0..63 within wg
  const float cbz = cb[gcz];
  const float cbr = cb[512 + gcz];
  const float cbh = cb[1024 + gcz];

  // ---- U weights -> registers (B-fragments, 192 VGPRs) ----
  short8 uzr[16], urr[16], uhr[16];
  #pragma unroll
  for (int k = 0; k < 16; ++k) {
    const int off = l16 * 512 + k * 32 + lhi * 8;
    uzr[k] = *(const short8*)(UTz + off);
    urr[k] = *(const short8*)(UTr + off);
    uhr[k] = *(const short8*)(UTh + off);
  }

  // ---- prologue: x_0 -> LDS, x_1 -> regs, h_lds = 0, x_0@W -> accumulators ----
  float4 xr4[8];
  {
    const float4* xs = (const float4*)(x + (size_t)r0 * D_);
    #pragma unroll
    for (int i = 0; i < 8; ++i) {
      int g = tid + i * 256;
      float4 v = xs[(g >> 7) * 128 + (g & 127)];
      unsigned short tmp[4] = { f2bf(v.x), f2bf(v.y), f2bf(v.z), f2bf(v.w) };
      *(unsigned long long*)&x_lds[0][g >> 7][(g & 127) * 4] = *(unsigned long long*)tmp;
      *(unsigned long long*)&h_lds[g >> 7][(g & 127) * 4] = 0ull;
    }
    const float4* xs1 = (const float4*)(x + ((size_t)B_ + r0) * D_);
    #pragma unroll
    for (int i = 0; i < 8; ++i) {
      int g = tid + i * 256;
      xr4[i] = xs1[(g >> 7) * 128 + (g & 127)];
    }
  }
  __syncthreads();

  f32x4 xzc = {0.f,0.f,0.f,0.f}, xrc = {0.f,0.f,0.f,0.f}, xhc = {0.f,0.f,0.f,0.f};
  {
    const unsigned short* xrow = &x_lds[0][l16][0];
    #pragma unroll
    for (int k = 0; k < 16; ++k) {
      int ko = k * 32 + lhi * 8;
      short8 ax = *(const short8*)(xrow + ko);
      int boff = l16 * 512 + ko;
      short8 wz = *(const short8*)(WTz + boff);
      short8 wr = *(const short8*)(WTr + boff);
      short8 wh = *(const short8*)(WTh + boff);
      xzc = __builtin_amdgcn_mfma_f32_16x16x32_bf16(ax, wz, xzc, 0, 0, 0);
      xrc = __builtin_amdgcn_mfma_f32_16x16x32_bf16(ax, wr, xrc, 0, 0, 0);
      xhc = __builtin_amdgcn_mfma_f32_16x16x32_bf16(ax, wh, xhc, 0, 0, 0);
    }
  }

  for (int t = 0; t < T_; ++t) {
    const int p = t & 1;
    // ---- phase A: h@Uz, h@Ur (U in regs, A from h_lds) ----
    f32x4 accz = {0.f,0.f,0.f,0.f};
    f32x4 accr = {0.f,0.f,0.f,0.f};
    {
      const unsigned short* hrow = &h_lds[l16][0];
      #pragma unroll
      for (int k = 0; k < 16; ++k) {
        short8 ah = *(const short8*)(hrow + k * 32 + lhi * 8);
        accz = __builtin_amdgcn_mfma_f32_16x16x32_bf16(ah, uzr[k], accz, 0, 0, 0);
        accr = __builtin_amdgcn_mfma_f32_16x16x32_bf16(ah, urr[k], accr, 0, 0, 0);
      }
    }
    // epilogue A: z, (1-z)h in regs; r*h -> pub (LDS repack)
    f32x4 z4, gh4;
    #pragma unroll
    for (int i = 0; i < 4; ++i) {
      int lrow = lhi * 4 + i;                  // C/D: row=(lane>>4)*4+i, col=lane&15
      float h_old = bf2f(h_lds[lrow][gcz]);
      float zv = 1.f / (1.f + __expf(-(accz[i] + xzc[i] + cbz)));
      float rv = 1.f / (1.f + __expf(-(accr[i] + xrc[i] + cbr)));
      z4[i]  = zv;
      gh4[i] = (1.f - zv) * h_old;
      pub[lrow][lcol] = f2bf(rv * h_old);
    }
    __syncthreads();
    {  // coalesced publish: one 8B store/thread, 128B segments
      int row = tid >> 4, c4 = (tid & 15) * 4;
      unsigned long long v = *(const unsigned long long*)&pub[row][c4];
      unsigned short* dst = rhbuf + (size_t)(r0 + row) * H_ + c0 + c4;
      if (fast) *(volatile unsigned long long*)dst = v;
      else __hip_atomic_store((unsigned long long*)dst, v,
                              __ATOMIC_RELAXED, __HIP_MEMORY_SCOPE_AGENT);
    }
    __syncthreads();                           // vmcnt(0) drain for all waves
    if (tid == 0) {
      if (fast) *myfast = FBASE + 2 * t + 1;
      else __hip_atomic_store(myslow, 2 * t + 1,
                              __ATOMIC_RELAXED, __HIP_MEMORY_SCOPE_AGENT);
    }

    // ---- stage x_{t+1} regs -> LDS ----
    #pragma unroll
    for (int i = 0; i < 8; ++i) {
      int g = tid + i * 256;
      float4 v = xr4[i];
      unsigned short tmp[4] = { f2bf(v.x), f2bf(v.y), f2bf(v.z), f2bf(v.w) };
      *(unsigned long long*)&x_lds[p ^ 1][g >> 7][(g & 127) * 4] = *(unsigned long long*)tmp;
    }
    __syncthreads();

    // ---- bubbles: xz_next, xr_next (hide peer skew + flag latency) ----
    f32x4 xzn = {0.f,0.f,0.f,0.f}, xrn = {0.f,0.f,0.f,0.f}, xhn = {0.f,0.f,0.f,0.f};
    {
      const unsigned short* xrow = &x_lds[p ^ 1][l16][0];
      #pragma unroll
      for (int k = 0; k < 16; ++k) {
        int ko = k * 32 + lhi * 8;
        short8 ax = *(const short8*)(xrow + ko);
        short8 wz = *(const short8*)(WTz + l16 * 512 + ko);
        short8 wr = *(const short8*)(WTr + l16 * 512 + ko);
        xzn = __builtin_amdgcn_mfma_f32_16x16x32_bf16(ax, wz, xzn, 0, 0, 0);
        xrn = __builtin_amdgcn_mfma_f32_16x16x32_bf16(ax, wr, xrn, 0, 0, 0);
      }
    }
    // ---- wait barrier 1 (bounded) ----
    if (tid < GRP) {
      int lim = 0;
      if (fast) {
        volatile int* p1 = (volatile int*)(fastf + tid * 32);
        while (*p1 < FBASE + 2 * t + 1) { if (++lim > (1 << 17)) break; }
      } else {
        int* p1 = slowf + tid * 32;
        while (__hip_atomic_load(p1, __ATOMIC_RELAXED, __HIP_MEMORY_SCOPE_AGENT)
               < 2 * t + 1) { if (++lim > (1 << 17)) break; }
      }
    }
    __syncthreads();

    // ---- load rh (issue), bubble xr already done; stage to LDS ----
    {
      unsigned long long rtmp[8];
      if (fast) {
        const volatile unsigned long long* base =
            (const volatile unsigned long long*)(rhbuf + (size_t)r0 * H_);
        #pragma unroll
        for (int i = 0; i < 8; ++i) {
          int g = tid + i * 256;
          rtmp[i] = base[(g >> 7) * 128 + (g & 127)];
        }
      } else {
        const unsigned long long* base = (const unsigned long long*)(rhbuf + (size_t)r0 * H_);
        #pragma unroll
        for (int i = 0; i < 8; ++i) {
          int g = tid + i * 256;
          rtmp[i] = __hip_atomic_load(base + (g >> 7) * 128 + (g & 127),
                                      __ATOMIC_RELAXED, __HIP_MEMORY_SCOPE_AGENT);
        }
      }
      #pragma unroll
      for (int i = 0; i < 8; ++i) {
        int g = tid + i * 256;
        *(unsigned long long*)&h_lds[g >> 7][(g & 127) * 4] = rtmp[i];
      }
    }
    __syncthreads();

    // ---- phase B: rh@Uh; h update; publish h ----
    f32x4 acc2 = {0.f,0.f,0.f,0.f};
    {
      const unsigned short* rrow = &h_lds[l16][0];
      #pragma unroll
      for (int k = 0; k < 16; ++k) {
        short8 ar = *(const short8*)(rrow + k * 32 + lhi * 8);
        acc2 = __builtin_amdgcn_mfma_f32_16x16x32_bf16(ar, uhr[k], acc2, 0, 0, 0);
      }
    }
    #pragma unroll
    for (int i = 0; i < 4; ++i) {
      int lrow = lhi * 4 + i;
      float hh = tanhf(acc2[i] + xhc[i] + cbh);
      float hn = gh4[i] + z4[i] * hh;
      pub[lrow][lcol] = f2bf(hn);
    }
    __syncthreads();
    {
      int row = tid >> 4, c4 = (tid & 15) * 4;
      unsigned long long v = *(const unsigned long long*)&pub[row][c4];
      unsigned short* dst = hbuf + (size_t)(r0 + row) * H_ + c0 + c4;
      if (fast) *(volatile unsigned long long*)dst = v;
      else __hip_atomic_store((unsigned long long*)dst, v,
                              __ATOMIC_RELAXED, __HIP_MEMORY_SCOPE_AGENT);
    }
    __syncthreads();
    if (tid == 0) {
      if (fast) *myfast = FBASE + 2 * t + 2;
      else __hip_atomic_store(myslow, 2 * t + 2,
                              __ATOMIC_RELAXED, __HIP_MEMORY_SCOPE_AGENT);
    }

    // ---- issue x_{t+2} prefetch; bubble xh_next ----
    {
      int tn = (t + 2 < T_) ? (t + 2) : (T_ - 1);
      const float4* xs = (const float4*)(x + ((size_t)tn * B_ + r0) * D_);
      #pragma unroll
      for (int i = 0; i < 8; ++i) {
        int g = tid + i * 256;
        xr4[i] = xs[(g >> 7) * 128 + (g & 127)];
      }
    }
    {
      const unsigned short* xrow = &x_lds[p ^ 1][l16][0];
      #pragma unroll
      for (int k = 0; k < 16; ++k) {
        int ko = k * 32 + lhi * 8;
        short8 ax = *(const short8*)(xrow + ko);
        short8 wh = *(const short8*)(WTh + l16 * 512 + ko);
        xhn = __builtin_amdgcn_mfma_f32_16x16x32_bf16(ax, wh, xhn, 0, 0, 0);
      }
    }
    // ---- wait barrier 2 (bounded) ----
    if (tid < GRP) {
      int lim = 0;
      if (fast) {
        volatile int* p2 = (volatile int*)(fastf + tid * 32);
        while (*p2 < FBASE + 2 * t + 2) { if (++lim > (1 << 17)) break; }
      } else {
        int* p2 = slowf + tid * 32;
        while (__hip_atomic_load(p2, __ATOMIC_RELAXED, __HIP_MEMORY_SCOPE_AGENT)
               < 2 * t + 2) { if (++lim > (1 << 17)) break; }
      }
    }
    __syncthreads();

    // ---- load h, stage to LDS ----
    {
      unsigned long long htmp[8];
      if (fast) {
        const volatile unsigned long long* base =
            (const volatile unsigned long long*)(hbuf + (size_t)r0 * H_);
        #pragma unroll
        for (int i = 0; i < 8; ++i) {
          int g = tid + i * 256;
          htmp[i] = base[(g >> 7) * 128 + (g & 127)];
        }
      } else {
        const unsigned long long* base = (const unsigned long long*)(hbuf + (size_t)r0 * H_);
        #pragma unroll
        for (int i = 0; i < 8; ++i) {
          int g = tid + i * 256;
          htmp[i] = __hip_atomic_load(base + (g >> 7) * 128 + (g & 127),
                                      __ATOMIC_RELAXED, __HIP_MEMORY_SCOPE_AGENT);
        }
      }
      #pragma unroll
      for (int i = 0; i < 8; ++i) {
        int g = tid + i * 256;
        *(unsigned long long*)&h_lds[g >> 7][(g & 127) * 4] = htmp[i];
      }
    }
    xzc = xzn; xrc = xrn; xhc = xhn;
    __syncthreads();
  }
}

// ---- final FC: out[b][o] = sum_k h_T[b][k] * fc_w[k][o] + fc_b[o]
__global__ void fc_kernel(const unsigned short* __restrict__ hbuf,
                          const float* __restrict__ fcw,
                          const float* __restrict__ fcb,
                          float* __restrict__ out)
{
  int b = blockIdx.x;
  int o = threadIdx.x;
  float s = fcb[o];
  const unsigned short* hr = hbuf + (size_t)b * H_;
  #pragma unroll 8
  for (int k = 0; k < H_; ++k)
    s = fmaf(bf2f(hr[k]), fcw[k * O_ + o], s);
  out[b * O_ + o] = s;
}

extern "C" void kernel_launch(void* const* d_in, const int* in_sizes, int n_in,
                              void* d_out, int out_size, void* d_ws, size_t ws_size,
                              hipStream_t stream)
{
  const float* x    = (const float*)d_in[0];
  const float* w_z  = (const float*)d_in[1];
  const float* b_z  = (const float*)d_in[2];
  const float* u_z  = (const float*)d_in[3];
  const float* ub_z = (const float*)d_in[4];
  const float* w_r  = (const float*)d_in[5];
  const float* b_r  = (const float*)d_in[6];
  const float* u_r  = (const float*)d_in[7];
  const float* ub_r = (const float*)d_in[8];
  const float* w_h  = (const float*)d_in[9];
  const float* b_h  = (const float*)d_in[10];
  const float* u_h  = (const float*)d_in[11];
  const float* ub_h = (const float*)d_in[12];
  const float* fc_w = (const float*)d_in[13];
  const float* fc_b = (const float*)d_in[14];
  float* out = (float*)d_out;

  char* ws = (char*)d_ws;
  unsigned short* WT = (unsigned short*)ws;  ws += (size_t)1536 * 512 * 2;
  unsigned short* UT = (unsigned short*)ws;  ws += (size_t)1536 * 512 * 2;
  float* cb = (float*)ws;                    ws += 1536 * 4;
  unsigned short* hbuf = (unsigned short*)ws;  ws += (size_t)B_ * H_ * 2;
  unsigned short* rhbuf = (unsigned short*)ws; ws += (size_t)B_ * H_ * 2;
  ws = (char*)(((size_t)ws + 255) & ~(size_t)255);
  int* bar = (int*)ws;

  prep_kernel<<<3072, 256, 0, stream>>>(w_z, u_z, w_r, u_r, w_h, u_h,
                                        b_z, ub_z, b_r, ub_r, b_h, ub_h,
                                        WT, UT, cb, hbuf, bar);
  gru_scan<<<NWG, 256, 0, stream>>>(x, WT, UT, cb, hbuf, rhbuf, bar);
  fc_kernel<<<B_, O_, 0, stream>>>(hbuf, fc_w, fc_b, out);
}

// Round 7
// 6478.076 us; speedup vs baseline: 1.1128x; 1.1128x over previous
//
#include <hip/hip_runtime.h>

// GRU T=512 B=256 D=512 H=512 O=256
// R7: R6 structure (static XCD grouping wgid&7 + calibration consensus +
// bounded polls + AGENT-scope fallback) with the fast path rebuilt on
// inline-asm sc0-only ops (bypass L1, served by local XCD L2):
//   - batched 8-wide staging loads, single s_waitcnt (pipelined)
//   - sc0 publish stores, explicit per-wave vmcnt(0) drain before barrier
//   - sc0 flag store / bounded sc0 flag poll
// Calibration ping-pong uses the SAME primitives; failure -> proven slow path.
// No s_getreg, no buffer_inv, no unbounded spins.

#define T_ 512
#define B_ 256
#define D_ 512
#define H_ 512
#define O_ 256

#define NWG 128
#define ROWS 16   // batch rows per wg
#define GC 64     // cols per gate per wg
#define GRP 8     // wgs per exchange group (one batch-group)
#define FBASE 8   // main-loop fast-flag values start here (calibration uses 1..3)

typedef __attribute__((ext_vector_type(8))) short short8;
typedef __attribute__((ext_vector_type(4))) float f32x4;

__device__ __forceinline__ unsigned short f2bf(float f) {
  unsigned u = __float_as_uint(f);
  u = (u + 0x7FFFu + ((u >> 16) & 1u)) >> 16;   // RNE
  return (unsigned short)u;
}
__device__ __forceinline__ float bf2f(unsigned short h) {
  return __uint_as_float(((unsigned)h) << 16);
}

// ---- sc0-only primitives: bypass L1, coherent at the local XCD L2 ----
__device__ __forceinline__ void st8_sc0(unsigned short* p, unsigned long long v) {
  asm volatile("global_store_dwordx2 %0, %1, off sc0" :: "v"(p), "v"(v) : "memory");
}
__device__ __forceinline__ void st4_sc0(int* p, int v) {
  asm volatile("global_store_dword %0, %1, off sc0" :: "v"(p), "v"(v) : "memory");
}
__device__ __forceinline__ int ld4_sc0(const int* p) {
  int r;
  asm volatile("global_load_dword %0, %1, off sc0\n\ts_waitcnt vmcnt(0)"
               : "=v"(r) : "v"(p) : "memory");
  return r;
}
#define EXCH_LD8_SC0(r, a)                                        \
  asm volatile(                                                   \
    "global_load_dwordx2 %0, %8, off sc0\n\t"                     \
    "global_load_dwordx2 %1, %9, off sc0\n\t"                     \
    "global_load_dwordx2 %2, %10, off sc0\n\t"                    \
    "global_load_dwordx2 %3, %11, off sc0\n\t"                    \
    "global_load_dwordx2 %4, %12, off sc0\n\t"                    \
    "global_load_dwordx2 %5, %13, off sc0\n\t"                    \
    "global_load_dwordx2 %6, %14, off sc0\n\t"                    \
    "global_load_dwordx2 %7, %15, off sc0\n\t"                    \
    "s_waitcnt vmcnt(0)"                                          \
    : "=&v"(r[0]), "=&v"(r[1]), "=&v"(r[2]), "=&v"(r[3]),         \
      "=&v"(r[4]), "=&v"(r[5]), "=&v"(r[6]), "=&v"(r[7])          \
    : "v"(a[0]), "v"(a[1]), "v"(a[2]), "v"(a[3]),                 \
      "v"(a[4]), "v"(a[5]), "v"(a[6]), "v"(a[7])                  \
    : "memory")

// ---- prep: transpose weights to N-major bf16, combine biases, zero h + flags
__global__ void prep_kernel(const float* wz, const float* uz,
                            const float* wr, const float* ur,
                            const float* wh, const float* uh,
                            const float* bz, const float* ubz,
                            const float* br, const float* ubr,
                            const float* bh, const float* ubh,
                            unsigned short* WT, unsigned short* UT,
                            float* cb, unsigned short* hbuf, int* bar)
{
  int idx = blockIdx.x * 256 + threadIdx.x;
  if (idx < 1536 * 512) {
    int n = idx >> 9;          // output col 0..1535 (z|r|h)
    int k = idx & 511;
    int g = n >> 9;            // gate
    int c = n & 511;
    const float* w = (g == 0) ? wz : (g == 1) ? wr : wh;
    const float* u = (g == 0) ? uz : (g == 1) ? ur : uh;
    WT[idx] = f2bf(w[k * H_ + c]);   // WT[n][k] = W[k][n]
    UT[idx] = f2bf(u[k * H_ + c]);
  }
  if (idx < 1536) {
    int g = idx >> 9, c = idx & 511;
    const float* b  = (g == 0) ? bz  : (g == 1) ? br  : bh;
    const float* ub = (g == 0) ? ubz : (g == 1) ? ubr : ubh;
    cb[idx] = b[c] + ub[c];
  }
  if (idx < B_ * H_) hbuf[idx] = 0;
  if (idx < 12288) bar[idx] = 0;   // [0:4096) slow flags, [4096:8192) fast, [8192:12288) obs
}

// ---- persistent scan kernel
__global__ __launch_bounds__(256, 1) void gru_scan(
    const float* __restrict__ x,            // [T][B][D] fp32
    const unsigned short* __restrict__ WT,  // [1536][512] bf16 N-major
    const unsigned short* __restrict__ UT,  // [1536][512] bf16 N-major
    const float* __restrict__ cb,           // [1536] combined bias
    unsigned short* hbuf,                   // [B][H] bf16
    unsigned short* rhbuf,                  // [B][H] bf16
    int* bar)
{
  __shared__ __align__(16) unsigned short x_lds[2][ROWS][520];
  __shared__ __align__(16) unsigned short h_lds[ROWS][520];
  __shared__ __align__(8)  unsigned short pub[ROWS][GC];
  __shared__ int s_ok, s_fast;

  const int tid = threadIdx.x;
  const int wid = tid >> 6;       // wave 0..3
  const int lane = tid & 63;
  const int l16 = lane & 15;
  const int lhi = lane >> 4;      // 0..3

  // ---- static XCD-based grouping (verified by calibration below) ----
  const int wgid = blockIdx.x;
  const int xcd = wgid & 7;       // expected XCD under round-robin dispatch
  const int sub = wgid >> 3;      // 0..15 within XCD
  const int bg = xcd * 2 + (sub >> 3);   // batch-group 0..15
  const int cg = sub & 7;                // member 0..7
  const int r0 = bg * ROWS;
  const int c0 = cg * GC;

  int* slowf = bar + bg * 256;           // 8 members x 32-int stride
  int* fastf = bar + 4096 + bg * 256;
  int* obsf  = bar + 8192 + bg * 256;

  // ---- calibration: does the sc0/L2 path propagate within this group? ----
  if (tid == 0) s_ok = 1;
  __syncthreads();
  for (int r = 1; r <= 3; ++r) {
    if (wid == 0) {
      if (lane == 0) st4_sc0(fastf + cg * 32, r);
      int vote = 1;
      if (lane < GRP) {
        const int* p = fastf + lane * 32;
        int lim = 0;
        const int bound = (r == 1) ? (1 << 16) : 8192;  // round 1 absorbs launch skew
        while (ld4_sc0(p) < r) { if (++lim > bound) { vote = 0; break; } }
      }
      unsigned long long b = __ballot(vote);
      if (lane == 0) { if ((b & 0xFFull) != 0xFFull) s_ok = 0; }
    }
    __syncthreads();
  }
  if (tid == 0)
    __hip_atomic_store(obsf + cg * 32, s_ok ? 2 : 1,
                       __ATOMIC_RELAXED, __HIP_MEMORY_SCOPE_AGENT);
  if (wid == 0) {
    int vote = 1;
    if (lane < GRP) {
      int lim = 0, v = 0;
      while ((v = __hip_atomic_load(obsf + lane * 32,
                                    __ATOMIC_RELAXED, __HIP_MEMORY_SCOPE_AGENT)) == 0) {
        if (++lim > (1 << 20)) { v = 1; break; }   // fail-safe -> slow
        __builtin_amdgcn_s_sleep(1);
      }
      vote = (v == 2);
    }
    unsigned long long b = __ballot(vote);
    if (lane == 0) s_fast = ((b & 0xFFull) == 0xFFull) ? 1 : 0;
  }
  __syncthreads();
  const int fast = s_fast;   // wg-uniform; consensus-consistent across the group

  int* myslow = slowf + cg * 32;
  int* myfast = fastf + cg * 32;

  const int ct = c0 + wid * 16;   // this wave's 16-col tile base (per gate)
  const unsigned short* WTz = WT + (size_t)(ct)        * 512;
  const unsigned short* WTr = WT + (size_t)(512 + ct)  * 512;
  const unsigned short* WTh = WT + (size_t)(1024 + ct) * 512;
  const unsigned short* UTz = UT + (size_t)(ct)        * 512;
  const unsigned short* UTr = UT + (size_t)(512 + ct)  * 512;
  const unsigned short* UTh = UT + (size_t)(1024 + ct) * 512;

  const int gcz  = ct + l16;      // this lane's gate column (0..511)
  const int lcol = ct - c0 + l16; // 0..63 within wg
  const float cbz = cb[gcz];
  const float cbr = cb[512 + gcz];
  const float cbh = cb[1024 + gcz];

  // ---- U weights -> registers (B-fragments) ----
  short8 uzr[16], urr[16], uhr[16];
  #pragma unroll
  for (int k = 0; k < 16; ++k) {
    const int off = l16 * 512 + k * 32 + lhi * 8;
    uzr[k] = *(const short8*)(UTz + off);
    urr[k] = *(const short8*)(UTr + off);
    uhr[k] = *(const short8*)(UTh + off);
  }

  // ---- prologue: x_0 -> LDS, x_1 -> regs, h_lds = 0, x_0@W -> accumulators ----
  float4 xr4[8];
  {
    const float4* xs = (const float4*)(x + (size_t)r0 * D_);
    #pragma unroll
    for (int i = 0; i < 8; ++i) {
      int g = tid + i * 256;
      float4 v = xs[(g >> 7) * 128 + (g & 127)];
      unsigned short tmp[4] = { f2bf(v.x), f2bf(v.y), f2bf(v.z), f2bf(v.w) };
      *(unsigned long long*)&x_lds[0][g >> 7][(g & 127) * 4] = *(unsigned long long*)tmp;
      *(unsigned long long*)&h_lds[g >> 7][(g & 127) * 4] = 0ull;
    }
    const float4* xs1 = (const float4*)(x + ((size_t)B_ + r0) * D_);
    #pragma unroll
    for (int i = 0; i < 8; ++i) {
      int g = tid + i * 256;
      xr4[i] = xs1[(g >> 7) * 128 + (g & 127)];
    }
  }
  __syncthreads();

  f32x4 xzc = {0.f,0.f,0.f,0.f}, xrc = {0.f,0.f,0.f,0.f}, xhc = {0.f,0.f,0.f,0.f};
  {
    const unsigned short* xrow = &x_lds[0][l16][0];
    #pragma unroll
    for (int k = 0; k < 16; ++k) {
      int ko = k * 32 + lhi * 8;
      short8 ax = *(const short8*)(xrow + ko);
      int boff = l16 * 512 + ko;
      short8 wz = *(const short8*)(WTz + boff);
      short8 wr = *(const short8*)(WTr + boff);
      short8 wh = *(const short8*)(WTh + boff);
      xzc = __builtin_amdgcn_mfma_f32_16x16x32_bf16(ax, wz, xzc, 0, 0, 0);
      xrc = __builtin_amdgcn_mfma_f32_16x16x32_bf16(ax, wr, xrc, 0, 0, 0);
      xhc = __builtin_amdgcn_mfma_f32_16x16x32_bf16(ax, wh, xhc, 0, 0, 0);
    }
  }

  for (int t = 0; t < T_; ++t) {
    const int p = t & 1;
    // ---- phase A: h@Uz, h@Ur (U in regs, A from h_lds) ----
    f32x4 accz = {0.f,0.f,0.f,0.f};
    f32x4 accr = {0.f,0.f,0.f,0.f};
    {
      const unsigned short* hrow = &h_lds[l16][0];
      #pragma unroll
      for (int k = 0; k < 16; ++k) {
        short8 ah = *(const short8*)(hrow + k * 32 + lhi * 8);
        accz = __builtin_amdgcn_mfma_f32_16x16x32_bf16(ah, uzr[k], accz, 0, 0, 0);
        accr = __builtin_amdgcn_mfma_f32_16x16x32_bf16(ah, urr[k], accr, 0, 0, 0);
      }
    }
    // epilogue A: z, (1-z)h in regs; r*h -> pub (LDS repack)
    f32x4 z4, gh4;
    #pragma unroll
    for (int i = 0; i < 4; ++i) {
      int lrow = lhi * 4 + i;                  // C/D: row=(lane>>4)*4+i, col=lane&15
      float h_old = bf2f(h_lds[lrow][gcz]);
      float zv = 1.f / (1.f + __expf(-(accz[i] + xzc[i] + cbz)));
      float rv = 1.f / (1.f + __expf(-(accr[i] + xrc[i] + cbr)));
      z4[i]  = zv;
      gh4[i] = (1.f - zv) * h_old;
      pub[lrow][lcol] = f2bf(rv * h_old);
    }
    __syncthreads();
    // ---- publish rh (coalesced 8B/thread); overlap x-stage with store acks ----
    {
      int row = tid >> 4, c4 = (tid & 15) * 4;
      unsigned long long v = *(const unsigned long long*)&pub[row][c4];
      unsigned short* dst = rhbuf + (size_t)(r0 + row) * H_ + c0 + c4;
      if (fast) st8_sc0(dst, v);
      else __hip_atomic_store((unsigned long long*)dst, v,
                              __ATOMIC_RELAXED, __HIP_MEMORY_SCOPE_AGENT);
    }
    #pragma unroll
    for (int i = 0; i < 8; ++i) {            // stage x_{t+1} regs -> LDS
      int g = tid + i * 256;
      float4 v = xr4[i];
      unsigned short tmp[4] = { f2bf(v.x), f2bf(v.y), f2bf(v.z), f2bf(v.w) };
      *(unsigned long long*)&x_lds[p ^ 1][g >> 7][(g & 127) * 4] = *(unsigned long long*)tmp;
    }
    asm volatile("s_waitcnt vmcnt(0)" ::: "memory");   // per-wave publish drain
    __syncthreads();
    if (tid == 0) {
      if (fast) st4_sc0(myfast, FBASE + 2 * t + 1);
      else __hip_atomic_store(myslow, 2 * t + 1,
                              __ATOMIC_RELAXED, __HIP_MEMORY_SCOPE_AGENT);
    }

    // ---- bubbles: xz_next, xr_next (hide peer skew + flag latency) ----
    f32x4 xzn = {0.f,0.f,0.f,0.f}, xrn = {0.f,0.f,0.f,0.f}, xhn = {0.f,0.f,0.f,0.f};
    {
      const unsigned short* xrow = &x_lds[p ^ 1][l16][0];
      #pragma unroll
      for (int k = 0; k < 16; ++k) {
        int ko = k * 32 + lhi * 8;
        short8 ax = *(const short8*)(xrow + ko);
        short8 wz = *(const short8*)(WTz + l16 * 512 + ko);
        short8 wr = *(const short8*)(WTr + l16 * 512 + ko);
        xzn = __builtin_amdgcn_mfma_f32_16x16x32_bf16(ax, wz, xzn, 0, 0, 0);
        xrn = __builtin_amdgcn_mfma_f32_16x16x32_bf16(ax, wr, xrn, 0, 0, 0);
      }
    }
    // ---- wait barrier 1 (bounded) ----
    if (tid < GRP) {
      int lim = 0;
      if (fast) {
        const int* p1 = fastf + tid * 32;
        while (ld4_sc0(p1) < FBASE + 2 * t + 1) { if (++lim > (1 << 17)) break; }
      } else {
        int* p1 = slowf + tid * 32;
        while (__hip_atomic_load(p1, __ATOMIC_RELAXED, __HIP_MEMORY_SCOPE_AGENT)
               < 2 * t + 1) { if (++lim > (1 << 17)) break; }
      }
    }
    __syncthreads();

    // ---- load rh (batched, pipelined), stage to LDS ----
    {
      unsigned long long rtmp[8];
      const unsigned long long* base = (const unsigned long long*)(rhbuf + (size_t)r0 * H_)
                                       + (tid >> 7) * 128 + (tid & 127);
      if (fast) {
        const unsigned long long* a[8];
        #pragma unroll
        for (int i = 0; i < 8; ++i) a[i] = base + i * 256;
        EXCH_LD8_SC0(rtmp, a);
      } else {
        #pragma unroll
        for (int i = 0; i < 8; ++i)
          rtmp[i] = __hip_atomic_load(base + i * 256,
                                      __ATOMIC_RELAXED, __HIP_MEMORY_SCOPE_AGENT);
      }
      #pragma unroll
      for (int i = 0; i < 8; ++i) {
        int g = tid + i * 256;
        *(unsigned long long*)&h_lds[g >> 7][(g & 127) * 4] = rtmp[i];
      }
    }
    __syncthreads();

    // ---- phase B: rh@Uh; h update ----
    f32x4 acc2 = {0.f,0.f,0.f,0.f};
    {
      const unsigned short* rrow = &h_lds[l16][0];
      #pragma unroll
      for (int k = 0; k < 16; ++k) {
        short8 ar = *(const short8*)(rrow + k * 32 + lhi * 8);
        acc2 = __builtin_amdgcn_mfma_f32_16x16x32_bf16(ar, uhr[k], acc2, 0, 0, 0);
      }
    }
    #pragma unroll
    for (int i = 0; i < 4; ++i) {
      int lrow = lhi * 4 + i;
      float hh = tanhf(acc2[i] + xhc[i] + cbh);
      float hn = gh4[i] + z4[i] * hh;
      pub[lrow][lcol] = f2bf(hn);
    }
    __syncthreads();
    // ---- publish h; drain; flag ----
    {
      int row = tid >> 4, c4 = (tid & 15) * 4;
      unsigned long long v = *(const unsigned long long*)&pub[row][c4];
      unsigned short* dst = hbuf + (size_t)(r0 + row) * H_ + c0 + c4;
      if (fast) st8_sc0(dst, v);
      else __hip_atomic_store((unsigned long long*)dst, v,
                              __ATOMIC_RELAXED, __HIP_MEMORY_SCOPE_AGENT);
    }
    asm volatile("s_waitcnt vmcnt(0)" ::: "memory");
    __syncthreads();
    if (tid == 0) {
      if (fast) st4_sc0(myfast, FBASE + 2 * t + 2);
      else __hip_atomic_store(myslow, 2 * t + 2,
                              __ATOMIC_RELAXED, __HIP_MEMORY_SCOPE_AGENT);
    }

    // ---- bubble: xh_next ----
    {
      const unsigned short* xrow = &x_lds[p ^ 1][l16][0];
      #pragma unroll
      for (int k = 0; k < 16; ++k) {
        int ko = k * 32 + lhi * 8;
        short8 ax = *(const short8*)(xrow + ko);
        short8 wh = *(const short8*)(WTh + l16 * 512 + ko);
        xhn = __builtin_amdgcn_mfma_f32_16x16x32_bf16(ax, wh, xhn, 0, 0, 0);
      }
    }
    // ---- wait barrier 2 (bounded) ----
    if (tid < GRP) {
      int lim = 0;
      if (fast) {
        const int* p2 = fastf + tid * 32;
        while (ld4_sc0(p2) < FBASE + 2 * t + 2) { if (++lim > (1 << 17)) break; }
      } else {
        int* p2 = slowf + tid * 32;
        while (__hip_atomic_load(p2, __ATOMIC_RELAXED, __HIP_MEMORY_SCOPE_AGENT)
               < 2 * t + 2) { if (++lim > (1 << 17)) break; }
      }
    }
    __syncthreads();

    // ---- load h (batched), stage to LDS ----
    {
      unsigned long long htmp[8];
      const unsigned long long* base = (const unsigned long long*)(hbuf + (size_t)r0 * H_)
                                       + (tid >> 7) * 128 + (tid & 127);
      if (fast) {
        const unsigned long long* a[8];
        #pragma unroll
        for (int i = 0; i < 8; ++i) a[i] = base + i * 256;
        EXCH_LD8_SC0(htmp, a);
      } else {
        #pragma unroll
        for (int i = 0; i < 8; ++i)
          htmp[i] = __hip_atomic_load(base + i * 256,
                                      __ATOMIC_RELAXED, __HIP_MEMORY_SCOPE_AGENT);
      }
      #pragma unroll
      for (int i = 0; i < 8; ++i) {
        int g = tid + i * 256;
        *(unsigned long long*)&h_lds[g >> 7][(g & 127) * 4] = htmp[i];
      }
    }
    // ---- issue x_{t+2} prefetch LAST (max runway to next vmcnt drain) ----
    {
      int tn = (t + 2 < T_) ? (t + 2) : (T_ - 1);
      const float4* xs = (const float4*)(x + ((size_t)tn * B_ + r0) * D_);
      #pragma unroll
      for (int i = 0; i < 8; ++i) {
        int g = tid + i * 256;
        xr4[i] = xs[(g >> 7) * 128 + (g & 127)];
      }
    }
    xzc = xzn; xrc = xrn; xhc = xhn;
    __syncthreads();
  }
}

// ---- final FC: out[b][o] = sum_k h_T[b][k] * fc_w[k][o] + fc_b[o]
__global__ void fc_kernel(const unsigned short* __restrict__ hbuf,
                          const float* __restrict__ fcw,
                          const float* __restrict__ fcb,
                          float* __restrict__ out)
{
  int b = blockIdx.x;
  int o = threadIdx.x;
  float s = fcb[o];
  const unsigned short* hr = hbuf + (size_t)b * H_;
  #pragma unroll 8
  for (int k = 0; k < H_; ++k)
    s = fmaf(bf2f(hr[k]), fcw[k * O_ + o], s);
  out[b * O_ + o] = s;
}

extern "C" void kernel_launch(void* const* d_in, const int* in_sizes, int n_in,
                              void* d_out, int out_size, void* d_ws, size_t ws_size,
                              hipStream_t stream)
{
  const float* x    = (const float*)d_in[0];
  const float* w_z  = (const float*)d_in[1];
  const float* b_z  = (const float*)d_in[2];
  const float* u_z  = (const float*)d_in[3];
  const float* ub_z = (const float*)d_in[4];
  const float* w_r  = (const float*)d_in[5];
  const float* b_r  = (const float*)d_in[6];
  const float* u_r  = (const float*)d_in[7];
  const float* ub_r = (const float*)d_in[8];
  const float* w_h  = (const float*)d_in[9];
  const float* b_h  = (const float*)d_in[10];
  const float* u_h  = (const float*)d_in[11];
  const float* ub_h = (const float*)d_in[12];
  const float* fc_w = (const float*)d_in[13];
  const float* fc_b = (const float*)d_in[14];
  float* out = (float*)d_out;

  char* ws = (char*)d_ws;
  unsigned short* WT = (unsigned short*)ws;  ws += (size_t)1536 * 512 * 2;
  unsigned short* UT = (unsigned short*)ws;  ws += (size_t)1536 * 512 * 2;
  float* cb = (float*)ws;                    ws += 1536 * 4;
  unsigned short* hbuf = (unsigned short*)ws;  ws += (size_t)B_ * H_ * 2;
  unsigned short* rhbuf = (unsigned short*)ws; ws += (size_t)B_ * H_ * 2;
  ws = (char*)(((size_t)ws + 255) & ~(size_t)255);
  int* bar = (int*)ws;

  prep_kernel<<<3072, 256, 0, stream>>>(w_z, u_z, w_r, u_r, w_h, u_h,
                                        b_z, ub_z, b_r, ub_r, b_h, ub_h,
                                        WT, UT, cb, hbuf, bar);
  gru_scan<<<NWG, 256, 0, stream>>>(x, WT, UT, cb, hbuf, rhbuf, bar);
  fc_kernel<<<B_, O_, 0, stream>>>(hbuf, fc_w, fc_b, out);
}

// Round 8
// 6237.321 us; speedup vs baseline: 1.1558x; 1.0386x over previous
//
#include <hip/hip_runtime.h>

// GRU T=512 B=256 D=512 H=512 O=256
// R8: XCD-local exchange groups (static wgid&7 mapping, proven by R6's FETCH
// collapse) with an L1-immune fast path built ONLY on L2 atomics:
//   - publish/flag-set: plain stores (CDNA L1 is write-through -> lands in the
//     shared XCD L2; vmcnt drain + syncthreads orders data before flag)
//   - flag poll: global_atomic_add(p,0) rtn  -> executes in L2, never L1
//   - data consume: batched 8x global_atomic_add_x2(p,0) rtn, one waitcnt
// Epoch-based flag values (system-scope counter bumped in prep) + window
// compare (v-target < 64) make the protocol immune to poison/stale init:
// flags are NEVER zeroed. Calibration ping-pong (same primitives, bounded)
// verifies same-L2 propagation per group; reject -> R3-proven AGENT path.
// FC folded into the scan epilogue (h_T already in LDS) - no fc kernel.

#define T_ 512
#define B_ 256
#define D_ 512
#define H_ 512
#define O_ 256

#define NWG 128
#define ROWS 16   // batch rows per wg
#define GC 64     // cols per gate per wg
#define GRP 8     // wgs per exchange group (one batch-group)
#define FBASE 8   // main-loop flag offsets start here (calibration uses 1..3)
#define ECELL 12288

typedef __attribute__((ext_vector_type(8))) short short8;
typedef __attribute__((ext_vector_type(4))) float f32x4;

__device__ __forceinline__ unsigned short f2bf(float f) {
  unsigned u = __float_as_uint(f);
  u = (u + 0x7FFFu + ((u >> 16) & 1u)) >> 16;   // RNE
  return (unsigned short)u;
}
__device__ __forceinline__ float bf2f(unsigned short h) {
  return __uint_as_float(((unsigned)h) << 16);
}
// window compare: ready iff v in [t, t+64). Prior-epoch stale (= t-8192+k) and
// poison are (almost surely) outside the window; producer runs <=4 ahead.
__device__ __forceinline__ int ready(unsigned v, unsigned t) { return (v - t) < 64u; }

// L2-scope atomic poll: RMW executes in the local XCD L2 (never L1). sc0=rtn.
__device__ __forceinline__ int poll_l2(int* p) {
  int r;
  asm volatile("global_atomic_add %0, %1, %2, off sc0\n\ts_waitcnt vmcnt(0)"
               : "=v"(r) : "v"(p), "v"(0) : "memory");
  return r;
}
// batched 8x 8B atomic-load (add 0, rtn) -> fresh local-L2 reads, pipelined
#define EXCH_ALD8(r, a, z)                                        \
  asm volatile(                                                   \
    "global_atomic_add_x2 %0, %8, %16, off sc0\n\t"               \
    "global_atomic_add_x2 %1, %9, %16, off sc0\n\t"               \
    "global_atomic_add_x2 %2, %10, %16, off sc0\n\t"              \
    "global_atomic_add_x2 %3, %11, %16, off sc0\n\t"              \
    "global_atomic_add_x2 %4, %12, %16, off sc0\n\t"              \
    "global_atomic_add_x2 %5, %13, %16, off sc0\n\t"              \
    "global_atomic_add_x2 %6, %14, %16, off sc0\n\t"              \
    "global_atomic_add_x2 %7, %15, %16, off sc0\n\t"              \
    "s_waitcnt vmcnt(0)"                                          \
    : "=&v"(r[0]), "=&v"(r[1]), "=&v"(r[2]), "=&v"(r[3]),         \
      "=&v"(r[4]), "=&v"(r[5]), "=&v"(r[6]), "=&v"(r[7])          \
    : "v"(a[0]), "v"(a[1]), "v"(a[2]), "v"(a[3]),                 \
      "v"(a[4]), "v"(a[5]), "v"(a[6]), "v"(a[7]), "v"(z)          \
    : "memory")

// ---- prep: transpose weights to N-major bf16, combine biases, bump epoch
__global__ void prep_kernel(const float* wz, const float* uz,
                            const float* wr, const float* ur,
                            const float* wh, const float* uh,
                            const float* bz, const float* ubz,
                            const float* br, const float* ubr,
                            const float* bh, const float* ubh,
                            unsigned short* WT, unsigned short* UT,
                            float* cb, int* bar)
{
  int idx = blockIdx.x * 256 + threadIdx.x;
  if (idx < 1536 * 512) {
    int n = idx >> 9;          // output col 0..1535 (z|r|h)
    int k = idx & 511;
    int g = n >> 9;            // gate
    int c = n & 511;
    const float* w = (g == 0) ? wz : (g == 1) ? wr : wh;
    const float* u = (g == 0) ? uz : (g == 1) ? ur : uh;
    WT[idx] = f2bf(w[k * H_ + c]);   // WT[n][k] = W[k][n]
    UT[idx] = f2bf(u[k * H_ + c]);
  }
  if (idx < 1536) {
    int g = idx >> 9, c = idx & 511;
    const float* b  = (g == 0) ? bz  : (g == 1) ? br  : bh;
    const float* ub = (g == 0) ? ubz : (g == 1) ? ubr : ubh;
    cb[idx] = b[c] + ub[c];
  }
  if (blockIdx.x == 0 && threadIdx.x == 0)
    __hip_atomic_fetch_add(&bar[ECELL], 1, __ATOMIC_RELAXED, __HIP_MEMORY_SCOPE_SYSTEM);
}

// ---- persistent scan kernel (+ fused FC epilogue)
__global__ __launch_bounds__(256, 1) void gru_scan(
    const float* __restrict__ x,            // [T][B][D] fp32
    const unsigned short* __restrict__ WT,  // [1536][512] bf16 N-major
    const unsigned short* __restrict__ UT,  // [1536][512] bf16 N-major
    const float* __restrict__ cb,           // [1536] combined bias
    unsigned short* hbuf,                   // [B][H] bf16
    unsigned short* rhbuf,                  // [B][H] bf16
    int* bar,
    const float* __restrict__ fcw,          // [512][256] f32
    const float* __restrict__ fcb,          // [256] f32
    float* __restrict__ out)                // [256][256] f32
{
  __shared__ __align__(16) unsigned short x_lds[2][ROWS][520];
  __shared__ __align__(16) unsigned short h_lds[ROWS][520];
  __shared__ __align__(8)  unsigned short pub[ROWS][GC];
  __shared__ int s_ok, s_fast;
  __shared__ unsigned s_base;

  const int tid = threadIdx.x;
  const int wid = tid >> 6;       // wave 0..3
  const int lane = tid & 63;
  const int l16 = lane & 15;
  const int lhi = lane >> 4;      // 0..3

  // ---- static XCD-based grouping (co-location verified by calibration) ----
  const int wgid = blockIdx.x;
  const int xcd = wgid & 7;
  const int sub = wgid >> 3;             // 0..15 within XCD
  const int bg = xcd * 2 + (sub >> 3);   // batch-group 0..15
  const int cg = sub & 7;                // member 0..7
  const int r0 = bg * ROWS;
  const int c0 = cg * GC;

  int* slowf = bar + bg * 256;           // 8 members x 32-int stride
  int* fastf = bar + 4096 + bg * 256;
  int* obsf  = bar + 8192 + bg * 256;

  // ---- epoch (system-coherent, bumped once per launch by prep) ----
  if (tid == 0)
    s_base = ((unsigned)__hip_atomic_load(&bar[ECELL], __ATOMIC_RELAXED,
                                          __HIP_MEMORY_SCOPE_SYSTEM)) << 13;
  __syncthreads();
  const unsigned base = s_base;

  // ---- calibration: same-L2 flag propagation via the exact fast primitives ----
  if (tid == 0) s_ok = 1;
  __syncthreads();
  for (int r = 1; r <= 3; ++r) {
    if (wid == 0) {
      if (lane == 0)
        __hip_atomic_store(fastf + cg * 32, (int)(base + r),
                           __ATOMIC_RELAXED, __HIP_MEMORY_SCOPE_WORKGROUP);
      int vote = 1;
      if (lane < GRP) {
        int* p = fastf + lane * 32;
        int lim = 0;
        const int bound = (r == 1) ? 8192 : 2048;
        while (!ready((unsigned)poll_l2(p), base + r)) {
          if (++lim > bound) { vote = 0; break; }
        }
      }
      unsigned long long b = __ballot(vote);
      if (lane == 0) { if ((b & 0xFFull) != 0xFFull) s_ok = 0; }
    }
    __syncthreads();
  }
  if (tid == 0)
    __hip_atomic_store(obsf + cg * 32, (int)(base + (s_ok ? 2 : 1)),
                       __ATOMIC_RELAXED, __HIP_MEMORY_SCOPE_AGENT);
  if (wid == 0) {
    int vote = 1;
    if (lane < GRP) {
      int lim = 0; unsigned v;
      for (;;) {
        v = (unsigned)__hip_atomic_load(obsf + lane * 32,
                                        __ATOMIC_RELAXED, __HIP_MEMORY_SCOPE_AGENT);
        if (ready(v, base + 1)) break;
        if (++lim > (1 << 20)) { v = base + 1; break; }   // fail-safe -> slow
        __builtin_amdgcn_s_sleep(1);
      }
      vote = (v == base + 2);
    }
    unsigned long long b = __ballot(vote);
    if (lane == 0) s_fast = ((b & 0xFFull) == 0xFFull) ? 1 : 0;
  }
  __syncthreads();
  const int fast = s_fast;

  int* myslow = slowf + cg * 32;
  int* myfast = fastf + cg * 32;

  const int ct = c0 + wid * 16;
  const unsigned short* WTz = WT + (size_t)(ct)        * 512;
  const unsigned short* WTr = WT + (size_t)(512 + ct)  * 512;
  const unsigned short* WTh = WT + (size_t)(1024 + ct) * 512;
  const unsigned short* UTz = UT + (size_t)(ct)        * 512;
  const unsigned short* UTr = UT + (size_t)(512 + ct)  * 512;
  const unsigned short* UTh = UT + (size_t)(1024 + ct) * 512;

  const int gcz  = ct + l16;
  const int lcol = ct - c0 + l16;
  const float cbz = cb[gcz];
  const float cbr = cb[512 + gcz];
  const float cbh = cb[1024 + gcz];

  // ---- U weights -> registers (B-fragments) ----
  short8 uzr[16], urr[16], uhr[16];
  #pragma unroll
  for (int k = 0; k < 16; ++k) {
    const int off = l16 * 512 + k * 32 + lhi * 8;
    uzr[k] = *(const short8*)(UTz + off);
    urr[k] = *(const short8*)(UTr + off);
    uhr[k] = *(const short8*)(UTh + off);
  }

  // ---- prologue: x_0 -> LDS, x_1 -> regs, h_lds = 0, x_0@W -> accumulators ----
  float4 xr4[8];
  {
    const float4* xs = (const float4*)(x + (size_t)r0 * D_);
    #pragma unroll
    for (int i = 0; i < 8; ++i) {
      int g = tid + i * 256;
      float4 v = xs[(g >> 7) * 128 + (g & 127)];
      unsigned short tmp[4] = { f2bf(v.x), f2bf(v.y), f2bf(v.z), f2bf(v.w) };
      *(unsigned long long*)&x_lds[0][g >> 7][(g & 127) * 4] = *(unsigned long long*)tmp;
      *(unsigned long long*)&h_lds[g >> 7][(g & 127) * 4] = 0ull;
    }
    const float4* xs1 = (const float4*)(x + ((size_t)B_ + r0) * D_);
    #pragma unroll
    for (int i = 0; i < 8; ++i) {
      int g = tid + i * 256;
      xr4[i] = xs1[(g >> 7) * 128 + (g & 127)];
    }
  }
  __syncthreads();

  f32x4 xzc = {0.f,0.f,0.f,0.f}, xrc = {0.f,0.f,0.f,0.f}, xhc = {0.f,0.f,0.f,0.f};
  {
    const unsigned short* xrow = &x_lds[0][l16][0];
    #pragma unroll
    for (int k = 0; k < 16; ++k) {
      int ko = k * 32 + lhi * 8;
      short8 ax = *(const short8*)(xrow + ko);
      int boff = l16 * 512 + ko;
      short8 wz = *(const short8*)(WTz + boff);
      short8 wr = *(const short8*)(WTr + boff);
      short8 wh = *(const short8*)(WTh + boff);
      xzc = __builtin_amdgcn_mfma_f32_16x16x32_bf16(ax, wz, xzc, 0, 0, 0);
      xrc = __builtin_amdgcn_mfma_f32_16x16x32_bf16(ax, wr, xrc, 0, 0, 0);
      xhc = __builtin_amdgcn_mfma_f32_16x16x32_bf16(ax, wh, xhc, 0, 0, 0);
    }
  }

  const unsigned long long zq = 0ull;

  for (int t = 0; t < T_; ++t) {
    const int p = t & 1;
    // ---- phase A: h@Uz, h@Ur ----
    f32x4 accz = {0.f,0.f,0.f,0.f};
    f32x4 accr = {0.f,0.f,0.f,0.f};
    {
      const unsigned short* hrow = &h_lds[l16][0];
      #pragma unroll
      for (int k = 0; k < 16; ++k) {
        short8 ah = *(const short8*)(hrow + k * 32 + lhi * 8);
        accz = __builtin_amdgcn_mfma_f32_16x16x32_bf16(ah, uzr[k], accz, 0, 0, 0);
        accr = __builtin_amdgcn_mfma_f32_16x16x32_bf16(ah, urr[k], accr, 0, 0, 0);
      }
    }
    // epilogue A: z, (1-z)h in regs; r*h -> pub (LDS repack)
    f32x4 z4, gh4;
    #pragma unroll
    for (int i = 0; i < 4; ++i) {
      int lrow = lhi * 4 + i;
      float h_old = bf2f(h_lds[lrow][gcz]);
      float zv = 1.f / (1.f + __expf(-(accz[i] + xzc[i] + cbz)));
      float rv = 1.f / (1.f + __expf(-(accr[i] + xrc[i] + cbr)));
      z4[i]  = zv;
      gh4[i] = (1.f - zv) * h_old;
      pub[lrow][lcol] = f2bf(rv * h_old);
    }
    __syncthreads();
    // ---- publish rh (plain write-through stores -> shared L2); stage x ----
    {
      int row = tid >> 4, c4 = (tid & 15) * 4;
      unsigned long long v = *(const unsigned long long*)&pub[row][c4];
      unsigned long long* dst = (unsigned long long*)
          (rhbuf + (size_t)(r0 + row) * H_ + c0 + c4);
      if (fast) *dst = v;
      else __hip_atomic_store(dst, v, __ATOMIC_RELAXED, __HIP_MEMORY_SCOPE_AGENT);
    }
    #pragma unroll
    for (int i = 0; i < 8; ++i) {            // stage x_{t+1} regs -> LDS
      int g = tid + i * 256;
      float4 v = xr4[i];
      unsigned short tmp[4] = { f2bf(v.x), f2bf(v.y), f2bf(v.z), f2bf(v.w) };
      *(unsigned long long*)&x_lds[p ^ 1][g >> 7][(g & 127) * 4] = *(unsigned long long*)tmp;
    }
    asm volatile("s_waitcnt vmcnt(0)" ::: "memory");   // per-wave publish drain
    __syncthreads();
    if (tid == 0) {
      if (fast) __hip_atomic_store(myfast, (int)(base + FBASE + 2 * t + 1),
                                   __ATOMIC_RELAXED, __HIP_MEMORY_SCOPE_WORKGROUP);
      else      __hip_atomic_store(myslow, (int)(base + FBASE + 2 * t + 1),
                                   __ATOMIC_RELAXED, __HIP_MEMORY_SCOPE_AGENT);
    }

    // ---- bubbles: xz_next, xr_next ----
    f32x4 xzn = {0.f,0.f,0.f,0.f}, xrn = {0.f,0.f,0.f,0.f}, xhn = {0.f,0.f,0.f,0.f};
    {
      const unsigned short* xrow = &x_lds[p ^ 1][l16][0];
      #pragma unroll
      for (int k = 0; k < 16; ++k) {
        int ko = k * 32 + lhi * 8;
        short8 ax = *(const short8*)(xrow + ko);
        short8 wz = *(const short8*)(WTz + l16 * 512 + ko);
        short8 wr = *(const short8*)(WTr + l16 * 512 + ko);
        xzn = __builtin_amdgcn_mfma_f32_16x16x32_bf16(ax, wz, xzn, 0, 0, 0);
        xrn = __builtin_amdgcn_mfma_f32_16x16x32_bf16(ax, wr, xrn, 0, 0, 0);
      }
    }
    // ---- wait barrier 1 (bounded; fast poll = L2 atomic) ----
    if (tid < GRP) {
      int lim = 0;
      if (fast) {
        while (!ready((unsigned)poll_l2(fastf + tid * 32), base + FBASE + 2 * t + 1))
          { if (++lim > (1 << 14)) break; }
      } else {
        while (!ready((unsigned)__hip_atomic_load(slowf + tid * 32, __ATOMIC_RELAXED,
                                                  __HIP_MEMORY_SCOPE_AGENT),
                      base + FBASE + 2 * t + 1))
          { if (++lim > (1 << 14)) break; }
      }
    }
    __syncthreads();

    // ---- load rh (L2-atomic batched), stage to LDS ----
    {
      unsigned long long rtmp[8];
      unsigned long long* bb = (unsigned long long*)(rhbuf + (size_t)r0 * H_)
                               + (tid >> 7) * 128 + (tid & 127);
      if (fast) {
        unsigned long long* a[8];
        #pragma unroll
        for (int i = 0; i < 8; ++i) a[i] = bb + i * 256;
        EXCH_ALD8(rtmp, a, zq);
      } else {
        #pragma unroll
        for (int i = 0; i < 8; ++i)
          rtmp[i] = __hip_atomic_load(bb + i * 256,
                                      __ATOMIC_RELAXED, __HIP_MEMORY_SCOPE_AGENT);
      }
      #pragma unroll
      for (int i = 0; i < 8; ++i) {
        int g = tid + i * 256;
        *(unsigned long long*)&h_lds[g >> 7][(g & 127) * 4] = rtmp[i];
      }
    }
    __syncthreads();

    // ---- phase B: rh@Uh; h update ----
    f32x4 acc2 = {0.f,0.f,0.f,0.f};
    {
      const unsigned short* rrow = &h_lds[l16][0];
      #pragma unroll
      for (int k = 0; k < 16; ++k) {
        short8 ar = *(const short8*)(rrow + k * 32 + lhi * 8);
        acc2 = __builtin_amdgcn_mfma_f32_16x16x32_bf16(ar, uhr[k], acc2, 0, 0, 0);
      }
    }
    #pragma unroll
    for (int i = 0; i < 4; ++i) {
      int lrow = lhi * 4 + i;
      float hh = tanhf(acc2[i] + xhc[i] + cbh);
      float hn = gh4[i] + z4[i] * hh;
      pub[lrow][lcol] = f2bf(hn);
    }
    __syncthreads();
    // ---- publish h; drain; flag ----
    {
      int row = tid >> 4, c4 = (tid & 15) * 4;
      unsigned long long v = *(const unsigned long long*)&pub[row][c4];
      unsigned long long* dst = (unsigned long long*)
          (hbuf + (size_t)(r0 + row) * H_ + c0 + c4);
      if (fast) *dst = v;
      else __hip_atomic_store(dst, v, __ATOMIC_RELAXED, __HIP_MEMORY_SCOPE_AGENT);
    }
    asm volatile("s_waitcnt vmcnt(0)" ::: "memory");
    __syncthreads();
    if (tid == 0) {
      if (fast) __hip_atomic_store(myfast, (int)(base + FBASE + 2 * t + 2),
                                   __ATOMIC_RELAXED, __HIP_MEMORY_SCOPE_WORKGROUP);
      else      __hip_atomic_store(myslow, (int)(base + FBASE + 2 * t + 2),
                                   __ATOMIC_RELAXED, __HIP_MEMORY_SCOPE_AGENT);
    }

    // ---- bubble: xh_next ----
    {
      const unsigned short* xrow = &x_lds[p ^ 1][l16][0];
      #pragma unroll
      for (int k = 0; k < 16; ++k) {
        int ko = k * 32 + lhi * 8;
        short8 ax = *(const short8*)(xrow + ko);
        short8 wh = *(const short8*)(WTh + l16 * 512 + ko);
        xhn = __builtin_amdgcn_mfma_f32_16x16x32_bf16(ax, wh, xhn, 0, 0, 0);
      }
    }
    // ---- wait barrier 2 (bounded) ----
    if (tid < GRP) {
      int lim = 0;
      if (fast) {
        while (!ready((unsigned)poll_l2(fastf + tid * 32), base + FBASE + 2 * t + 2))
          { if (++lim > (1 << 14)) break; }
      } else {
        while (!ready((unsigned)__hip_atomic_load(slowf + tid * 32, __ATOMIC_RELAXED,
                                                  __HIP_MEMORY_SCOPE_AGENT),
                      base + FBASE + 2 * t + 2))
          { if (++lim > (1 << 14)) break; }
      }
    }
    __syncthreads();

    // ---- load h (L2-atomic batched), stage to LDS ----
    {
      unsigned long long htmp[8];
      unsigned long long* bb = (unsigned long long*)(hbuf + (size_t)r0 * H_)
                               + (tid >> 7) * 128 + (tid & 127);
      if (fast) {
        unsigned long long* a[8];
        #pragma unroll
        for (int i = 0; i < 8; ++i) a[i] = bb + i * 256;
        EXCH_ALD8(htmp, a, zq);
      } else {
        #pragma unroll
        for (int i = 0; i < 8; ++i)
          htmp[i] = __hip_atomic_load(bb + i * 256,
                                      __ATOMIC_RELAXED, __HIP_MEMORY_SCOPE_AGENT);
      }
      #pragma unroll
      for (int i = 0; i < 8; ++i) {
        int g = tid + i * 256;
        *(unsigned long long*)&h_lds[g >> 7][(g & 127) * 4] = htmp[i];
      }
    }
    // ---- issue x_{t+2} prefetch ----
    {
      int tn = (t + 2 < T_) ? (t + 2) : (T_ - 1);
      const float4* xs = (const float4*)(x + ((size_t)tn * B_ + r0) * D_);
      #pragma unroll
      for (int i = 0; i < 8; ++i) {
        int g = tid + i * 256;
        xr4[i] = xs[(g >> 7) * 128 + (g & 127)];
      }
    }
    xzc = xzn; xrc = xrn; xhc = xhn;
    __syncthreads();
  }

  // ---- fused FC epilogue: out[r0..r0+16][cg*32..+32] = h_T @ fc_w + fc_b ----
  // h_lds holds h_T rows r0..r0+16 (staged at end of t=T-1). Waves 0-1 work.
  if (wid < 2) {
    const int cfc = cg * 32 + wid * 16 + l16;   // output col 0..255
    f32x4 acc = {0.f,0.f,0.f,0.f};
    const unsigned short* hrow = &h_lds[l16][0];
    #pragma unroll
    for (int k0 = 0; k0 < 512; k0 += 32) {
      int ko = k0 + lhi * 8;
      short8 ah = *(const short8*)(hrow + ko);
      short8 bw;
      #pragma unroll
      for (int j = 0; j < 8; ++j)
        bw[j] = (short)f2bf(fcw[(size_t)(ko + j) * O_ + cfc]);
      acc = __builtin_amdgcn_mfma_f32_16x16x32_bf16(ah, bw, acc, 0, 0, 0);
    }
    float bb = fcb[cfc];
    #pragma unroll
    for (int i = 0; i < 4; ++i)
      out[(size_t)(r0 + lhi * 4 + i) * O_ + cfc] = acc[i] + bb;
  }
}

extern "C" void kernel_launch(void* const* d_in, const int* in_sizes, int n_in,
                              void* d_out, int out_size, void* d_ws, size_t ws_size,
                              hipStream_t stream)
{
  const float* x    = (const float*)d_in[0];
  const float* w_z  = (const float*)d_in[1];
  const float* b_z  = (const float*)d_in[2];
  const float* u_z  = (const float*)d_in[3];
  const float* ub_z = (const float*)d_in[4];
  const float* w_r  = (const float*)d_in[5];
  const float* b_r  = (const float*)d_in[6];
  const float* u_r  = (const float*)d_in[7];
  const float* ub_r = (const float*)d_in[8];
  const float* w_h  = (const float*)d_in[9];
  const float* b_h  = (const float*)d_in[10];
  const float* u_h  = (const float*)d_in[11];
  const float* ub_h = (const float*)d_in[12];
  const float* fc_w = (const float*)d_in[13];
  const float* fc_b = (const float*)d_in[14];
  float* out = (float*)d_out;

  char* ws = (char*)d_ws;
  unsigned short* WT = (unsigned short*)ws;  ws += (size_t)1536 * 512 * 2;
  unsigned short* UT = (unsigned short*)ws;  ws += (size_t)1536 * 512 * 2;
  float* cb = (float*)ws;                    ws += 1536 * 4;
  unsigned short* hbuf = (unsigned short*)ws;  ws += (size_t)B_ * H_ * 2;
  unsigned short* rhbuf = (unsigned short*)ws; ws += (size_t)B_ * H_ * 2;
  ws = (char*)(((size_t)ws + 255) & ~(size_t)255);
  int* bar = (int*)ws;

  prep_kernel<<<3072, 256, 0, stream>>>(w_z, u_z, w_r, u_r, w_h, u_h,
                                        b_z, ub_z, b_r, ub_r, b_h, ub_h,
                                        WT, UT, cb, bar);
  gru_scan<<<NWG, 256, 0, stream>>>(x, WT, UT, cb, hbuf, rhbuf, bar,
                                    fc_w, fc_b, out);
}

// Round 9
// 5652.084 us; speedup vs baseline: 1.2754x; 1.1035x over previous
//
#include <hip/hip_runtime.h>

// GRU T=512 B=256 D=512 H=512 O=256
// R9: XCD-local exchange (static wgid&7 groups; co-location proven in R6).
// Fast path primitives, each individually HW-proven in earlier rounds:
//   publish  = plain write-through stores + per-wave vmcnt drain   (R8-proven)
//   flag set = plain store; flag poll = sc0 atomic add(0) in L2    (R8-proven)
//   consume  = s_waitcnt vmcnt(0); buffer_inv sc1 (L1 invalidate, the
//              compiler's own agent-acquire instruction) + plain coalesced
//              global_load_dwordx4 from fresh local L2              (NEW)
// Calibration per group: 3 rounds of flag ping-pong AND data round-trip
// (rounds 2-3 re-read an L1-resident cell after inv -> genuine stale test).
// Any failure -> R3-proven AGENT-scope slow path. All spins bounded.
// Epoch+window flag values: immune to poison / prior-launch state.

#define T_ 512
#define B_ 256
#define D_ 512
#define H_ 512
#define O_ 256

#define NWG 128
#define ROWS 16   // batch rows per wg
#define GC 64     // cols per gate per wg
#define GRP 8     // wgs per exchange group (one batch-group)
#define FBASE 8   // main-loop flag offsets start here (calibration uses 1..3)
#define ECELL 12288
#define DCELL 12352

typedef __attribute__((ext_vector_type(8))) short short8;
typedef __attribute__((ext_vector_type(4))) float f32x4;
typedef __attribute__((ext_vector_type(4))) unsigned int uint4v;

__device__ __forceinline__ unsigned short f2bf(float f) {
  unsigned u = __float_as_uint(f);
  u = (u + 0x7FFFu + ((u >> 16) & 1u)) >> 16;   // RNE
  return (unsigned short)u;
}
__device__ __forceinline__ float bf2f(unsigned short h) {
  return __uint_as_float(((unsigned)h) << 16);
}
// ready iff v in [t, t+64): prior-epoch stale and 0xAA poison fall outside.
__device__ __forceinline__ int ready(unsigned v, unsigned t) { return (v - t) < 64u; }

// L2-executed atomic poll (sc0 = return old). Never served by L1. [R8-proven]
__device__ __forceinline__ int poll_l2(int* p) {
  int r;
  asm volatile("global_atomic_add %0, %1, %2, off sc0\n\ts_waitcnt vmcnt(0)"
               : "=v"(r) : "v"(p), "v"(0) : "memory");
  return r;
}
// Drain outstanding VMEM, then invalidate vector L1 (compiler-standard
// agent-acquire sequence). Subsequent plain loads refill from local L2.
__device__ __forceinline__ void inv_l1() {
  asm volatile("s_waitcnt vmcnt(0)\n\tbuffer_inv sc1" ::: "memory");
}

// ---- prep: transpose weights to N-major bf16, combine biases, bump epoch
__global__ void prep_kernel(const float* wz, const float* uz,
                            const float* wr, const float* ur,
                            const float* wh, const float* uh,
                            const float* bz, const float* ubz,
                            const float* br, const float* ubr,
                            const float* bh, const float* ubh,
                            unsigned short* WT, unsigned short* UT,
                            float* cb, int* bar)
{
  int idx = blockIdx.x * 256 + threadIdx.x;
  if (idx < 1536 * 512) {
    int n = idx >> 9;          // output col 0..1535 (z|r|h)
    int k = idx & 511;
    int g = n >> 9;            // gate
    int c = n & 511;
    const float* w = (g == 0) ? wz : (g == 1) ? wr : wh;
    const float* u = (g == 0) ? uz : (g == 1) ? ur : uh;
    WT[idx] = f2bf(w[k * H_ + c]);   // WT[n][k] = W[k][n]
    UT[idx] = f2bf(u[k * H_ + c]);
  }
  if (idx < 1536) {
    int g = idx >> 9, c = idx & 511;
    const float* b  = (g == 0) ? bz  : (g == 1) ? br  : bh;
    const float* ub = (g == 0) ? ubz : (g == 1) ? ubr : ubh;
    cb[idx] = b[c] + ub[c];
  }
  if (blockIdx.x == 0 && threadIdx.x == 0)
    __hip_atomic_fetch_add(&bar[ECELL], 1, __ATOMIC_RELAXED, __HIP_MEMORY_SCOPE_SYSTEM);
}

// ---- persistent scan kernel (+ fused FC epilogue)
__global__ __launch_bounds__(256, 1) void gru_scan(
    const float* __restrict__ x,            // [T][B][D] fp32
    const unsigned short* __restrict__ WT,  // [1536][512] bf16 N-major
    const unsigned short* __restrict__ UT,  // [1536][512] bf16 N-major
    const float* __restrict__ cb,           // [1536] combined bias
    unsigned short* hbuf,                   // [B][H] bf16
    unsigned short* rhbuf,                  // [B][H] bf16
    int* bar,
    const float* __restrict__ fcw,          // [512][256] f32
    const float* __restrict__ fcb,          // [256] f32
    float* __restrict__ out)                // [256][256] f32
{
  __shared__ __align__(16) unsigned short x_lds[2][ROWS][520];
  __shared__ __align__(16) unsigned short h_lds[ROWS][520];
  __shared__ __align__(8)  unsigned short pub[ROWS][GC];
  __shared__ int s_ok, s_fast;
  __shared__ unsigned s_base;

  const int tid = threadIdx.x;
  const int wid = tid >> 6;       // wave 0..3
  const int lane = tid & 63;
  const int l16 = lane & 15;
  const int lhi = lane >> 4;      // 0..3

  // ---- static XCD-based grouping ----
  const int wgid = blockIdx.x;
  const int xcd = wgid & 7;
  const int sub = wgid >> 3;             // 0..15 within XCD
  const int bg = xcd * 2 + (sub >> 3);   // batch-group 0..15
  const int cg = sub & 7;                // member 0..7
  const int r0 = bg * ROWS;
  const int c0 = cg * GC;

  int* slowf = bar + bg * 256;           // 8 members x 32-int stride
  int* fastf = bar + 4096 + bg * 256;
  int* obsf  = bar + 8192 + bg * 256;
  int* dataf = bar + DCELL + bg * 256;   // calibration data cells (16B used/32)

  // ---- epoch ----
  if (tid == 0)
    s_base = ((unsigned)__hip_atomic_load(&bar[ECELL], __ATOMIC_RELAXED,
                                          __HIP_MEMORY_SCOPE_SYSTEM)) << 13;
  __syncthreads();
  const unsigned base = s_base;

  // ---- calibration: flag ping-pong + data round-trip via the fast recipe ----
  if (tid == 0) s_ok = 1;
  __syncthreads();
  for (int r = 1; r <= 3; ++r) {
    if (wid == 0) {
      if (lane == 0) {
        // fresh data each round into my cell (plain write-through stores)
        uint4v dv = { base + r, base + r + 101u, base + r + 202u, base + r + 303u };
        *(uint4v*)(dataf + cg * 32) = dv;
        asm volatile("s_waitcnt vmcnt(0)" ::: "memory");   // data at L2
        __hip_atomic_store(fastf + cg * 32, (int)(base + r),
                           __ATOMIC_RELAXED, __HIP_MEMORY_SCOPE_WORKGROUP);
      }
      int vote = 1;
      if (lane < GRP) {
        int* p = fastf + lane * 32;
        int lim = 0;
        const int bound = (r == 1) ? 8192 : 2048;
        while (!ready((unsigned)poll_l2(p), base + r)) {
          if (++lim > bound) { vote = 0; break; }
        }
      }
      inv_l1();                        // wave-level; all lanes reconverged
      if (lane < GRP && vote) {
        uint4v dv = *(const uint4v*)(dataf + lane * 32);   // plain load
        if (dv.x != base + r || dv.y != base + r + 101u ||
            dv.z != base + r + 202u || dv.w != base + r + 303u) vote = 0;
      }
      unsigned long long b = __ballot(vote);
      if (lane == 0) { if ((b & 0xFFull) != 0xFFull) s_ok = 0; }
    }
    __syncthreads();
  }
  if (tid == 0)
    __hip_atomic_store(obsf + cg * 32, (int)(base + (s_ok ? 2 : 1)),
                       __ATOMIC_RELAXED, __HIP_MEMORY_SCOPE_AGENT);
  if (wid == 0) {
    int vote = 1;
    if (lane < GRP) {
      int lim = 0; unsigned v;
      for (;;) {
        v = (unsigned)__hip_atomic_load(obsf + lane * 32,
                                        __ATOMIC_RELAXED, __HIP_MEMORY_SCOPE_AGENT);
        if (ready(v, base + 1)) break;
        if (++lim > (1 << 20)) { v = base + 1; break; }   // fail-safe -> slow
        __builtin_amdgcn_s_sleep(1);
      }
      vote = (v == base + 2);
    }
    unsigned long long b = __ballot(vote);
    if (lane == 0) s_fast = ((b & 0xFFull) == 0xFFull) ? 1 : 0;
  }
  __syncthreads();
  const int fast = s_fast;

  int* myslow = slowf + cg * 32;
  int* myfast = fastf + cg * 32;

  const int ct = c0 + wid * 16;
  const unsigned short* WTz = WT + (size_t)(ct)        * 512;
  const unsigned short* WTr = WT + (size_t)(512 + ct)  * 512;
  const unsigned short* WTh = WT + (size_t)(1024 + ct) * 512;
  const unsigned short* UTz = UT + (size_t)(ct)        * 512;
  const unsigned short* UTr = UT + (size_t)(512 + ct)  * 512;
  const unsigned short* UTh = UT + (size_t)(1024 + ct) * 512;

  const int gcz  = ct + l16;
  const int lcol = ct - c0 + l16;
  const float cbz = cb[gcz];
  const float cbr = cb[512 + gcz];
  const float cbh = cb[1024 + gcz];

  // ---- U weights -> registers (B-fragments) ----
  short8 uzr[16], urr[16], uhr[16];
  #pragma unroll
  for (int k = 0; k < 16; ++k) {
    const int off = l16 * 512 + k * 32 + lhi * 8;
    uzr[k] = *(const short8*)(UTz + off);
    urr[k] = *(const short8*)(UTr + off);
    uhr[k] = *(const short8*)(UTh + off);
  }

  // ---- prologue: x_0 -> LDS, x_1 -> regs, h_lds = 0, x_0@W -> accumulators ----
  float4 xr4[8];
  {
    const float4* xs = (const float4*)(x + (size_t)r0 * D_);
    #pragma unroll
    for (int i = 0; i < 8; ++i) {
      int g = tid + i * 256;
      float4 v = xs[(g >> 7) * 128 + (g & 127)];
      unsigned short tmp[4] = { f2bf(v.x), f2bf(v.y), f2bf(v.z), f2bf(v.w) };
      *(unsigned long long*)&x_lds[0][g >> 7][(g & 127) * 4] = *(unsigned long long*)tmp;
      *(unsigned long long*)&h_lds[g >> 7][(g & 127) * 4] = 0ull;
    }
    const float4* xs1 = (const float4*)(x + ((size_t)B_ + r0) * D_);
    #pragma unroll
    for (int i = 0; i < 8; ++i) {
      int g = tid + i * 256;
      xr4[i] = xs1[(g >> 7) * 128 + (g & 127)];
    }
  }
  __syncthreads();

  f32x4 xzc = {0.f,0.f,0.f,0.f}, xrc = {0.f,0.f,0.f,0.f}, xhc = {0.f,0.f,0.f,0.f};
  {
    const unsigned short* xrow = &x_lds[0][l16][0];
    #pragma unroll
    for (int k = 0; k < 16; ++k) {
      int ko = k * 32 + lhi * 8;
      short8 ax = *(const short8*)(xrow + ko);
      int boff = l16 * 512 + ko;
      short8 wz = *(const short8*)(WTz + boff);
      short8 wr = *(const short8*)(WTr + boff);
      short8 wh = *(const short8*)(WTh + boff);
      xzc = __builtin_amdgcn_mfma_f32_16x16x32_bf16(ax, wz, xzc, 0, 0, 0);
      xrc = __builtin_amdgcn_mfma_f32_16x16x32_bf16(ax, wr, xrc, 0, 0, 0);
      xhc = __builtin_amdgcn_mfma_f32_16x16x32_bf16(ax, wh, xhc, 0, 0, 0);
    }
  }

  for (int t = 0; t < T_; ++t) {
    const int p = t & 1;
    // ---- phase A: h@Uz, h@Ur ----
    f32x4 accz = {0.f,0.f,0.f,0.f};
    f32x4 accr = {0.f,0.f,0.f,0.f};
    {
      const unsigned short* hrow = &h_lds[l16][0];
      #pragma unroll
      for (int k = 0; k < 16; ++k) {
        short8 ah = *(const short8*)(hrow + k * 32 + lhi * 8);
        accz = __builtin_amdgcn_mfma_f32_16x16x32_bf16(ah, uzr[k], accz, 0, 0, 0);
        accr = __builtin_amdgcn_mfma_f32_16x16x32_bf16(ah, urr[k], accr, 0, 0, 0);
      }
    }
    // epilogue A: z, (1-z)h in regs; r*h -> pub (LDS repack)
    f32x4 z4, gh4;
    #pragma unroll
    for (int i = 0; i < 4; ++i) {
      int lrow = lhi * 4 + i;
      float h_old = bf2f(h_lds[lrow][gcz]);
      float zv = 1.f / (1.f + __expf(-(accz[i] + xzc[i] + cbz)));
      float rv = 1.f / (1.f + __expf(-(accr[i] + xrc[i] + cbr)));
      z4[i]  = zv;
      gh4[i] = (1.f - zv) * h_old;
      pub[lrow][lcol] = f2bf(rv * h_old);
    }
    __syncthreads();
    // ---- publish rh (plain write-through stores); stage x under the acks ----
    {
      int row = tid >> 4, c4 = (tid & 15) * 4;
      unsigned long long v = *(const unsigned long long*)&pub[row][c4];
      unsigned long long* dst = (unsigned long long*)
          (rhbuf + (size_t)(r0 + row) * H_ + c0 + c4);
      if (fast) *dst = v;
      else __hip_atomic_store(dst, v, __ATOMIC_RELAXED, __HIP_MEMORY_SCOPE_AGENT);
    }
    #pragma unroll
    for (int i = 0; i < 8; ++i) {            // stage x_{t+1} regs -> LDS
      int g = tid + i * 256;
      float4 v = xr4[i];
      unsigned short tmp[4] = { f2bf(v.x), f2bf(v.y), f2bf(v.z), f2bf(v.w) };
      *(unsigned long long*)&x_lds[p ^ 1][g >> 7][(g & 127) * 4] = *(unsigned long long*)tmp;
    }
    asm volatile("s_waitcnt vmcnt(0)" ::: "memory");   // per-wave publish drain
    __syncthreads();
    if (tid == 0) {
      if (fast) __hip_atomic_store(myfast, (int)(base + FBASE + 2 * t + 1),
                                   __ATOMIC_RELAXED, __HIP_MEMORY_SCOPE_WORKGROUP);
      else      __hip_atomic_store(myslow, (int)(base + FBASE + 2 * t + 1),
                                   __ATOMIC_RELAXED, __HIP_MEMORY_SCOPE_AGENT);
    }

    // ---- bubbles: xz_next, xr_next ----
    f32x4 xzn = {0.f,0.f,0.f,0.f}, xrn = {0.f,0.f,0.f,0.f}, xhn = {0.f,0.f,0.f,0.f};
    {
      const unsigned short* xrow = &x_lds[p ^ 1][l16][0];
      #pragma unroll
      for (int k = 0; k < 16; ++k) {
        int ko = k * 32 + lhi * 8;
        short8 ax = *(const short8*)(xrow + ko);
        short8 wz = *(const short8*)(WTz + l16 * 512 + ko);
        short8 wr = *(const short8*)(WTr + l16 * 512 + ko);
        xzn = __builtin_amdgcn_mfma_f32_16x16x32_bf16(ax, wz, xzn, 0, 0, 0);
        xrn = __builtin_amdgcn_mfma_f32_16x16x32_bf16(ax, wr, xrn, 0, 0, 0);
      }
    }
    // ---- wait barrier 1 (bounded; L2 atomic poll) ----
    if (tid < GRP) {
      int lim = 0;
      if (fast) {
        while (!ready((unsigned)poll_l2(fastf + tid * 32), base + FBASE + 2 * t + 1))
          { if (++lim > (1 << 14)) break; }
      } else {
        while (!ready((unsigned)__hip_atomic_load(slowf + tid * 32, __ATOMIC_RELAXED,
                                                  __HIP_MEMORY_SCOPE_AGENT),
                      base + FBASE + 2 * t + 1))
          { if (++lim > (1 << 14)) break; }
      }
    }
    __syncthreads();

    // ---- consume rh: inv L1 then plain coalesced dwordx4 from local L2 ----
    if (fast) {
      inv_l1();
      const uint4v* bb = (const uint4v*)(rhbuf + (size_t)r0 * H_);
      uint4v rv[4];
      #pragma unroll
      for (int i = 0; i < 4; ++i) rv[i] = bb[tid + i * 256];
      #pragma unroll
      for (int i = 0; i < 4; ++i)
        *(uint4v*)&h_lds[(tid >> 6) + i * 4][(tid & 63) * 8] = rv[i];
    } else {
      unsigned long long rtmp[8];
      unsigned long long* bb = (unsigned long long*)(rhbuf + (size_t)r0 * H_)
                               + (tid >> 7) * 128 + (tid & 127);
      #pragma unroll
      for (int i = 0; i < 8; ++i)
        rtmp[i] = __hip_atomic_load(bb + i * 256,
                                    __ATOMIC_RELAXED, __HIP_MEMORY_SCOPE_AGENT);
      #pragma unroll
      for (int i = 0; i < 8; ++i) {
        int g = tid + i * 256;
        *(unsigned long long*)&h_lds[g >> 7][(g & 127) * 4] = rtmp[i];
      }
    }
    __syncthreads();

    // ---- phase B: rh@Uh; h update ----
    f32x4 acc2 = {0.f,0.f,0.f,0.f};
    {
      const unsigned short* rrow = &h_lds[l16][0];
      #pragma unroll
      for (int k = 0; k < 16; ++k) {
        short8 ar = *(const short8*)(rrow + k * 32 + lhi * 8);
        acc2 = __builtin_amdgcn_mfma_f32_16x16x32_bf16(ar, uhr[k], acc2, 0, 0, 0);
      }
    }
    #pragma unroll
    for (int i = 0; i < 4; ++i) {
      int lrow = lhi * 4 + i;
      float hh = tanhf(acc2[i] + xhc[i] + cbh);
      float hn = gh4[i] + z4[i] * hh;
      pub[lrow][lcol] = f2bf(hn);
    }
    __syncthreads();
    // ---- publish h; drain; flag ----
    {
      int row = tid >> 4, c4 = (tid & 15) * 4;
      unsigned long long v = *(const unsigned long long*)&pub[row][c4];
      unsigned long long* dst = (unsigned long long*)
          (hbuf + (size_t)(r0 + row) * H_ + c0 + c4);
      if (fast) *dst = v;
      else __hip_atomic_store(dst, v, __ATOMIC_RELAXED, __HIP_MEMORY_SCOPE_AGENT);
    }
    asm volatile("s_waitcnt vmcnt(0)" ::: "memory");
    __syncthreads();
    if (tid == 0) {
      if (fast) __hip_atomic_store(myfast, (int)(base + FBASE + 2 * t + 2),
                                   __ATOMIC_RELAXED, __HIP_MEMORY_SCOPE_WORKGROUP);
      else      __hip_atomic_store(myslow, (int)(base + FBASE + 2 * t + 2),
                                   __ATOMIC_RELAXED, __HIP_MEMORY_SCOPE_AGENT);
    }

    // ---- bubble: xh_next ----
    {
      const unsigned short* xrow = &x_lds[p ^ 1][l16][0];
      #pragma unroll
      for (int k = 0; k < 16; ++k) {
        int ko = k * 32 + lhi * 8;
        short8 ax = *(const short8*)(xrow + ko);
        short8 wh = *(const short8*)(WTh + l16 * 512 + ko);
        xhn = __builtin_amdgcn_mfma_f32_16x16x32_bf16(ax, wh, xhn, 0, 0, 0);
      }
    }
    // ---- wait barrier 2 (bounded) ----
    if (tid < GRP) {
      int lim = 0;
      if (fast) {
        while (!ready((unsigned)poll_l2(fastf + tid * 32), base + FBASE + 2 * t + 2))
          { if (++lim > (1 << 14)) break; }
      } else {
        while (!ready((unsigned)__hip_atomic_load(slowf + tid * 32, __ATOMIC_RELAXED,
                                                  __HIP_MEMORY_SCOPE_AGENT),
                      base + FBASE + 2 * t + 2))
          { if (++lim > (1 << 14)) break; }
      }
    }
    __syncthreads();

    // ---- consume h: inv L1 then plain coalesced dwordx4 ----
    if (fast) {
      inv_l1();
      const uint4v* bb = (const uint4v*)(hbuf + (size_t)r0 * H_);
      uint4v hv[4];
      #pragma unroll
      for (int i = 0; i < 4; ++i) hv[i] = bb[tid + i * 256];
      #pragma unroll
      for (int i = 0; i < 4; ++i)
        *(uint4v*)&h_lds[(tid >> 6) + i * 4][(tid & 63) * 8] = hv[i];
    } else {
      unsigned long long htmp[8];
      unsigned long long* bb = (unsigned long long*)(hbuf + (size_t)r0 * H_)
                               + (tid >> 7) * 128 + (tid & 127);
      #pragma unroll
      for (int i = 0; i < 8; ++i)
        htmp[i] = __hip_atomic_load(bb + i * 256,
                                    __ATOMIC_RELAXED, __HIP_MEMORY_SCOPE_AGENT);
      #pragma unroll
      for (int i = 0; i < 8; ++i) {
        int g = tid + i * 256;
        *(unsigned long long*)&h_lds[g >> 7][(g & 127) * 4] = htmp[i];
      }
    }
    // ---- issue x_{t+2} prefetch ----
    {
      int tn = (t + 2 < T_) ? (t + 2) : (T_ - 1);
      const float4* xs = (const float4*)(x + ((size_t)tn * B_ + r0) * D_);
      #pragma unroll
      for (int i = 0; i < 8; ++i) {
        int g = tid + i * 256;
        xr4[i] = xs[(g >> 7) * 128 + (g & 127)];
      }
    }
    xzc = xzn; xrc = xrn; xhc = xhn;
    __syncthreads();
  }

  // ---- fused FC epilogue: out[r0..r0+16][cg*32..+32] = h_T @ fc_w + fc_b ----
  if (wid < 2) {
    const int cfc = cg * 32 + wid * 16 + l16;   // output col 0..255
    f32x4 acc = {0.f,0.f,0.f,0.f};
    const unsigned short* hrow = &h_lds[l16][0];
    #pragma unroll
    for (int k0 = 0; k0 < 512; k0 += 32) {
      int ko = k0 + lhi * 8;
      short8 ah = *(const short8*)(hrow + ko);
      short8 bw;
      #pragma unroll
      for (int j = 0; j < 8; ++j)
        bw[j] = (short)f2bf(fcw[(size_t)(ko + j) * O_ + cfc]);
      acc = __builtin_amdgcn_mfma_f32_16x16x32_bf16(ah, bw, acc, 0, 0, 0);
    }
    float bb = fcb[cfc];
    #pragma unroll
    for (int i = 0; i < 4; ++i)
      out[(size_t)(r0 + lhi * 4 + i) * O_ + cfc] = acc[i] + bb;
  }
}

extern "C" void kernel_launch(void* const* d_in, const int* in_sizes, int n_in,
                              void* d_out, int out_size, void* d_ws, size_t ws_size,
                              hipStream_t stream)
{
  const float* x    = (const float*)d_in[0];
  const float* w_z  = (const float*)d_in[1];
  const float* b_z  = (const float*)d_in[2];
  const float* u_z  = (const float*)d_in[3];
  const float* ub_z = (const float*)d_in[4];
  const float* w_r  = (const float*)d_in[5];
  const float* b_r  = (const float*)d_in[6];
  const float* u_r  = (const float*)d_in[7];
  const float* ub_r = (const float*)d_in[8];
  const float* w_h  = (const float*)d_in[9];
  const float* b_h  = (const float*)d_in[10];
  const float* u_h  = (const float*)d_in[11];
  const float* ub_h = (const float*)d_in[12];
  const float* fc_w = (const float*)d_in[13];
  const float* fc_b = (const float*)d_in[14];
  float* out = (float*)d_out;

  char* ws = (char*)d_ws;
  unsigned short* WT = (unsigned short*)ws;  ws += (size_t)1536 * 512 * 2;
  unsigned short* UT = (unsigned short*)ws;  ws += (size_t)1536 * 512 * 2;
  float* cb = (float*)ws;                    ws += 1536 * 4;
  unsigned short* hbuf = (unsigned short*)ws;  ws += (size_t)B_ * H_ * 2;
  unsigned short* rhbuf = (unsigned short*)ws; ws += (size_t)B_ * H_ * 2;
  ws = (char*)(((size_t)ws + 255) & ~(size_t)255);
  int* bar = (int*)ws;

  prep_kernel<<<3072, 256, 0, stream>>>(w_z, u_z, w_r, u_r, w_h, u_h,
                                        b_z, ub_z, b_r, ub_r, b_h, ub_h,
                                        WT, UT, cb, bar);
  gru_scan<<<NWG, 256, 0, stream>>>(x, WT, UT, cb, hbuf, rhbuf, bar,
                                    fc_w, fc_b, out);
}